// Round 1
// baseline (1180.526 us; speedup 1.0000x reference)
//
#include <hip/hip_runtime.h>

constexpr int BB   = 2;
constexpr int NN   = 50000;
constexpr int EE   = 600000;
constexpr int CDIM = 128;
constexpr int ODIM = 128;

// ---------------------------------------------------------------------------
// Scatter: 32 lanes per edge, each lane handles 4 contiguous floats (float4).
// x[b,t,:] += node[b,src,:] - rel[r,:]   via hardware f32 atomics.
// cnt[b,t] += 1 (lane 0).
// ---------------------------------------------------------------------------
__global__ __launch_bounds__(256) void scatter_k(
    const float* __restrict__ node, const int* __restrict__ eidx,
    const float* __restrict__ rel, float* __restrict__ acc,
    float* __restrict__ cnt)
{
    int tid  = blockIdx.x * 256 + threadIdx.x;
    int e    = tid >> 5;
    if (e >= EE) return;
    int lane = tid & 31;

    int b = eidx[e];
    int t = eidx[EE + e];
    int s = eidx[2 * EE + e];
    int r = eidx[3 * EE + e];

    int d4 = lane * 4;
    const float4 hv = *reinterpret_cast<const float4*>(
        node + (size_t)(b * NN + s) * CDIM + d4);
    const float4 rv = *reinterpret_cast<const float4*>(
        rel + (size_t)r * CDIM + d4);

    float* ap = acc + (size_t)(b * NN + t) * CDIM + d4;
    unsafeAtomicAdd(ap + 0, hv.x - rv.x);
    unsafeAtomicAdd(ap + 1, hv.y - rv.y);
    unsafeAtomicAdd(ap + 2, hv.z - rv.z);
    unsafeAtomicAdd(ap + 3, hv.w - rv.w);
    if (lane == 0) unsafeAtomicAdd(cnt + b * NN + t, 1.0f);
}

// ---------------------------------------------------------------------------
// Finish (in-place on `out`, which currently holds x = scattered sums):
//   out[row,:] = (x[row,:] @ W.T) / cnt[row]
// W (64 KB) transposed into LDS: Wt[d*128 + o] = W[o*128 + d].
// Block = 256 threads, 32 rows per block.
//   col thread ct = tid & 31  -> outputs ct*4 .. ct*4+3 (float4 LDS read)
//   row thread rt = tid >> 5  -> rows rowbase + rt*4 + j, j=0..3
// x rows read from global (L1 broadcast; 16 lanes share each address).
// __syncthreads() before the in-place store protects read-after-write.
// ---------------------------------------------------------------------------
__global__ __launch_bounds__(256) void finish_k(
    const float* __restrict__ W, const float* __restrict__ cnt,
    float* __restrict__ out)
{
    __shared__ float Wt[CDIM * ODIM];  // Wt[d][o], 64 KB
    const int tid = threadIdx.x;

    #pragma unroll
    for (int i = 0; i < 64; ++i) {
        int idx = tid + i * 256;
        int o = idx >> 7, d = idx & 127;
        Wt[d * 128 + o] = W[idx];
    }
    __syncthreads();

    const int rowbase = blockIdx.x * 32;
    const int ct = tid & 31;
    const int rt = tid >> 5;

    float acc[4][4];
    #pragma unroll
    for (int j = 0; j < 4; ++j)
        #pragma unroll
        for (int k = 0; k < 4; ++k) acc[j][k] = 0.f;

    const float* xrow0 = out + (size_t)(rowbase + rt * 4 + 0) * CDIM;
    const float* xrow1 = out + (size_t)(rowbase + rt * 4 + 1) * CDIM;
    const float* xrow2 = out + (size_t)(rowbase + rt * 4 + 2) * CDIM;
    const float* xrow3 = out + (size_t)(rowbase + rt * 4 + 3) * CDIM;

    for (int d = 0; d < CDIM; d += 4) {
        float4 xv0 = *reinterpret_cast<const float4*>(xrow0 + d);
        float4 xv1 = *reinterpret_cast<const float4*>(xrow1 + d);
        float4 xv2 = *reinterpret_cast<const float4*>(xrow2 + d);
        float4 xv3 = *reinterpret_cast<const float4*>(xrow3 + d);
        #pragma unroll
        for (int dd = 0; dd < 4; ++dd) {
            float4 w4 = *reinterpret_cast<const float4*>(&Wt[(d + dd) * 128 + ct * 4]);
            float x0 = dd == 0 ? xv0.x : dd == 1 ? xv0.y : dd == 2 ? xv0.z : xv0.w;
            float x1 = dd == 0 ? xv1.x : dd == 1 ? xv1.y : dd == 2 ? xv1.z : xv1.w;
            float x2 = dd == 0 ? xv2.x : dd == 1 ? xv2.y : dd == 2 ? xv2.z : xv2.w;
            float x3 = dd == 0 ? xv3.x : dd == 1 ? xv3.y : dd == 2 ? xv3.z : xv3.w;
            acc[0][0] += x0 * w4.x; acc[0][1] += x0 * w4.y;
            acc[0][2] += x0 * w4.z; acc[0][3] += x0 * w4.w;
            acc[1][0] += x1 * w4.x; acc[1][1] += x1 * w4.y;
            acc[1][2] += x1 * w4.z; acc[1][3] += x1 * w4.w;
            acc[2][0] += x2 * w4.x; acc[2][1] += x2 * w4.y;
            acc[2][2] += x2 * w4.z; acc[2][3] += x2 * w4.w;
            acc[3][0] += x3 * w4.x; acc[3][1] += x3 * w4.y;
            acc[3][2] += x3 * w4.z; acc[3][3] += x3 * w4.w;
        }
    }

    float inv0 = 1.0f / cnt[rowbase + rt * 4 + 0];
    float inv1 = 1.0f / cnt[rowbase + rt * 4 + 1];
    float inv2 = 1.0f / cnt[rowbase + rt * 4 + 2];
    float inv3 = 1.0f / cnt[rowbase + rt * 4 + 3];

    __syncthreads();  // all x reads done before in-place overwrite

    float4 y;
    y.x = acc[0][0] * inv0; y.y = acc[0][1] * inv0;
    y.z = acc[0][2] * inv0; y.w = acc[0][3] * inv0;
    *reinterpret_cast<float4*>(out + (size_t)(rowbase + rt * 4 + 0) * CDIM + ct * 4) = y;
    y.x = acc[1][0] * inv1; y.y = acc[1][1] * inv1;
    y.z = acc[1][2] * inv1; y.w = acc[1][3] * inv1;
    *reinterpret_cast<float4*>(out + (size_t)(rowbase + rt * 4 + 1) * CDIM + ct * 4) = y;
    y.x = acc[2][0] * inv2; y.y = acc[2][1] * inv2;
    y.z = acc[2][2] * inv2; y.w = acc[2][3] * inv2;
    *reinterpret_cast<float4*>(out + (size_t)(rowbase + rt * 4 + 2) * CDIM + ct * 4) = y;
    y.x = acc[3][0] * inv3; y.y = acc[3][1] * inv3;
    y.z = acc[3][2] * inv3; y.w = acc[3][3] * inv3;
    *reinterpret_cast<float4*>(out + (size_t)(rowbase + rt * 4 + 3) * CDIM + ct * 4) = y;
}

extern "C" void kernel_launch(void* const* d_in, const int* in_sizes, int n_in,
                              void* d_out, int out_size, void* d_ws, size_t ws_size,
                              hipStream_t stream) {
    const float* node = (const float*)d_in[0];
    const int*   eidx = (const int*)d_in[1];
    const float* rel  = (const float*)d_in[2];
    const float* W    = (const float*)d_in[3];
    float* out = (float*)d_out;
    float* cnt = (float*)d_ws;

    // zero the x-accumulator (d_out doubles as it) and counts
    hipMemsetAsync(d_out, 0, (size_t)out_size * sizeof(float), stream);
    hipMemsetAsync(cnt, 0, (size_t)(BB * NN) * sizeof(float), stream);

    // scatter: 32 threads per edge
    scatter_k<<<(EE * 32) / 256, 256, 0, stream>>>(node, eidx, rel, out, cnt);

    // finish: 32 rows per block
    finish_k<<<(BB * NN) / 32, 256, 0, stream>>>(W, cnt, out);
}

// Round 2
// 166.537 us; speedup vs baseline: 7.0887x; 7.0887x over previous
//
#include <hip/hip_runtime.h>

constexpr int BB   = 2;
constexpr int NN   = 50000;
constexpr int EE   = 600000;
constexpr int CDIM = 128;
constexpr int SEGS = BB * NN;          // 100000
constexpr int NIL  = 0xFFFFF;          // 20-bit sentinel (> EE-1)

// ---------------------------------------------------------------------------
// build_k: push each edge onto its segment's linked list.
//   head[seg]   = newest edge id (atomicExch, 600k atomics total)
//   nextpay[e]  = next(20b) | src(16b, N<65536) | rel(6b)  -- one 8B word so
//                 traversal costs a single random read per edge.
// ---------------------------------------------------------------------------
__global__ __launch_bounds__(256) void build_k(
    const int* __restrict__ eidx, int* __restrict__ head,
    unsigned long long* __restrict__ nextpay)
{
    int e = blockIdx.x * 256 + threadIdx.x;
    if (e >= EE) return;
    int b = eidx[e];
    int t = eidx[EE + e];
    int s = eidx[2 * EE + e];
    int r = eidx[3 * EE + e];
    int seg = b * NN + t;
    int old = atomicExch(head + seg, e);
    unsigned long long nx = (old < 0) ? (unsigned long long)NIL
                                      : (unsigned long long)old;
    nextpay[e] = nx | ((unsigned long long)s << 20)
                    | ((unsigned long long)r << 36);
}

// ---------------------------------------------------------------------------
// gather_k: 32 lanes per segment (128 floats as float4/lane), 8 segments per
// 256-thread block. Walk the chain, accumulate (h_src - r_rel) in registers,
// divide by degree (mean fused here -- linearity), write x row once.
// No atomics. Chains are lane-uniform per 32-lane group (broadcast loads).
// ---------------------------------------------------------------------------
__global__ __launch_bounds__(256) void gather_k(
    const float* __restrict__ node, const float* __restrict__ rel,
    const int* __restrict__ head,
    const unsigned long long* __restrict__ nextpay,
    float* __restrict__ x)
{
    int tid  = threadIdx.x;
    int seg  = blockIdx.x * 8 + (tid >> 5);
    int lane = tid & 31;
    int b    = (seg >= NN) ? 1 : 0;

    const float* nbase = node + (size_t)b * NN * CDIM + lane * 4;
    const float* rbase = rel + lane * 4;

    float4 acc = {0.f, 0.f, 0.f, 0.f};
    float  c   = 0.f;

    int e = head[seg];
    while (e >= 0) {
        unsigned long long np = nextpay[e];
        int s  = (int)((np >> 20) & 0xFFFF);
        int r  = (int)((np >> 36) & 0x3F);
        float4 hv = *reinterpret_cast<const float4*>(nbase + (size_t)s * CDIM);
        float4 rv = *reinterpret_cast<const float4*>(rbase + r * CDIM);
        acc.x += hv.x - rv.x;
        acc.y += hv.y - rv.y;
        acc.z += hv.z - rv.z;
        acc.w += hv.w - rv.w;
        c += 1.f;
        int nx = (int)(np & 0xFFFFF);
        e = (nx == NIL) ? -1 : nx;
    }

    float inv = 1.f / c;  // degree >= 1 guaranteed (cover edges)
    float4 y = {acc.x * inv, acc.y * inv, acc.z * inv, acc.w * inv};
    *reinterpret_cast<float4*>(x + (size_t)seg * CDIM + lane * 4) = y;
}

// ---------------------------------------------------------------------------
// finish_k (in-place on `out`, which holds x = per-segment means):
//   out[row,:] = x[row,:] @ W.T
// W transposed into LDS with a 16B-granule XOR swizzle so the staging writes
// spread across banks. Block = 256 threads, 32 rows/block, 4x4 reg tile.
// ---------------------------------------------------------------------------
__global__ __launch_bounds__(256) void finish_k(
    const float* __restrict__ W, float* __restrict__ out)
{
    __shared__ float Wt[CDIM * CDIM];  // Wt[d][o ^ swz(d)], 64 KB
    const int tid = threadIdx.x;

    #pragma unroll
    for (int i = 0; i < 64; ++i) {
        int idx = tid + i * 256;
        int o = idx >> 7, d = idx & 127;
        Wt[d * 128 + (o ^ ((d & 7) << 2))] = W[idx];
    }
    __syncthreads();

    const int rowbase = blockIdx.x * 32;
    const int ct = tid & 31;
    const int rt = tid >> 5;

    float acc[4][4];
    #pragma unroll
    for (int j = 0; j < 4; ++j)
        #pragma unroll
        for (int k = 0; k < 4; ++k) acc[j][k] = 0.f;

    const float* xrow0 = out + (size_t)(rowbase + rt * 4 + 0) * CDIM;
    const float* xrow1 = out + (size_t)(rowbase + rt * 4 + 1) * CDIM;
    const float* xrow2 = out + (size_t)(rowbase + rt * 4 + 2) * CDIM;
    const float* xrow3 = out + (size_t)(rowbase + rt * 4 + 3) * CDIM;

    for (int d = 0; d < CDIM; d += 4) {
        float4 xv0 = *reinterpret_cast<const float4*>(xrow0 + d);
        float4 xv1 = *reinterpret_cast<const float4*>(xrow1 + d);
        float4 xv2 = *reinterpret_cast<const float4*>(xrow2 + d);
        float4 xv3 = *reinterpret_cast<const float4*>(xrow3 + d);
        #pragma unroll
        for (int dd = 0; dd < 4; ++dd) {
            int dcur = d + dd;
            const float4 w4 = *reinterpret_cast<const float4*>(
                &Wt[dcur * 128 + ((ct * 4) ^ ((dcur & 7) << 2))]);
            float x0 = dd == 0 ? xv0.x : dd == 1 ? xv0.y : dd == 2 ? xv0.z : xv0.w;
            float x1 = dd == 0 ? xv1.x : dd == 1 ? xv1.y : dd == 2 ? xv1.z : xv1.w;
            float x2 = dd == 0 ? xv2.x : dd == 1 ? xv2.y : dd == 2 ? xv2.z : xv2.w;
            float x3 = dd == 0 ? xv3.x : dd == 1 ? xv3.y : dd == 2 ? xv3.z : xv3.w;
            acc[0][0] += x0 * w4.x; acc[0][1] += x0 * w4.y;
            acc[0][2] += x0 * w4.z; acc[0][3] += x0 * w4.w;
            acc[1][0] += x1 * w4.x; acc[1][1] += x1 * w4.y;
            acc[1][2] += x1 * w4.z; acc[1][3] += x1 * w4.w;
            acc[2][0] += x2 * w4.x; acc[2][1] += x2 * w4.y;
            acc[2][2] += x2 * w4.z; acc[2][3] += x2 * w4.w;
            acc[3][0] += x3 * w4.x; acc[3][1] += x3 * w4.y;
            acc[3][2] += x3 * w4.z; acc[3][3] += x3 * w4.w;
        }
    }

    __syncthreads();  // all x reads done before in-place overwrite

    float4 y;
    y.x = acc[0][0]; y.y = acc[0][1]; y.z = acc[0][2]; y.w = acc[0][3];
    *reinterpret_cast<float4*>(out + (size_t)(rowbase + rt * 4 + 0) * CDIM + ct * 4) = y;
    y.x = acc[1][0]; y.y = acc[1][1]; y.z = acc[1][2]; y.w = acc[1][3];
    *reinterpret_cast<float4*>(out + (size_t)(rowbase + rt * 4 + 1) * CDIM + ct * 4) = y;
    y.x = acc[2][0]; y.y = acc[2][1]; y.z = acc[2][2]; y.w = acc[2][3];
    *reinterpret_cast<float4*>(out + (size_t)(rowbase + rt * 4 + 2) * CDIM + ct * 4) = y;
    y.x = acc[3][0]; y.y = acc[3][1]; y.z = acc[3][2]; y.w = acc[3][3];
    *reinterpret_cast<float4*>(out + (size_t)(rowbase + rt * 4 + 3) * CDIM + ct * 4) = y;
}

extern "C" void kernel_launch(void* const* d_in, const int* in_sizes, int n_in,
                              void* d_out, int out_size, void* d_ws, size_t ws_size,
                              hipStream_t stream) {
    const float* node = (const float*)d_in[0];
    const int*   eidx = (const int*)d_in[1];
    const float* rel  = (const float*)d_in[2];
    const float* W    = (const float*)d_in[3];
    float* out = (float*)d_out;

    // ws layout: head int[SEGS] @ 0 (400000 B, 8B-aligned end), then nextpay u64[EE]
    int* head = (int*)d_ws;
    unsigned long long* nextpay =
        (unsigned long long*)((char*)d_ws + (size_t)SEGS * sizeof(int));

    hipMemsetAsync(head, 0xFF, (size_t)SEGS * sizeof(int), stream);  // head = -1

    build_k<<<(EE + 255) / 256, 256, 0, stream>>>(eidx, head, nextpay);
    gather_k<<<SEGS / 8, 256, 0, stream>>>(node, rel, head, nextpay, out);
    finish_k<<<SEGS / 32, 256, 0, stream>>>(W, out);
}